// Round 19
// baseline (250.908 us; speedup 1.0000x reference)
//
#include <hip/hip_runtime.h>
#include <hip/hip_bf16.h>
#include <stdint.h>

// T-structure as a signed permutation: for each (k,p) exactly one q with
// sign s such that T[k,p,q] = s. Transcribed from _TERMS.
__constant__ signed char QTAB[64] = {
    0,1,2,3,4,5,6,7,
    1,0,4,5,2,3,7,6,
    2,4,0,6,1,7,3,5,
    3,5,6,0,7,1,2,4,
    4,2,1,7,0,6,5,3,
    5,3,7,1,6,0,4,2,
    6,7,3,2,5,4,0,1,
    7,6,5,4,3,2,1,0};
__constant__ signed char SGN[64] = {
    1, 1, 1, 1,-1,-1,-1,-1,
    1, 1,-1, 1, 1,-1,-1,-1,
    1, 1, 1,-1,-1, 1, 1,-1,
    1,-1, 1, 1,-1,-1,-1, 1,
    1, 1,-1, 1, 1,-1, 1,-1,
    1,-1, 1, 1, 1, 1,-1,-1,
    1,-1,-1, 1,-1, 1, 1, 1,
    1, 1,-1, 1, 1,-1, 1, 1};

typedef __attribute__((ext_vector_type(8))) short bf16x8;
typedef __attribute__((ext_vector_type(4))) float f32x4;
typedef __attribute__((ext_vector_type(4))) unsigned int u32x4;

#define SBAR __builtin_amdgcn_sched_barrier(0)
#define WAITVM(N)                                         \
    asm volatile("s_waitcnt vmcnt(" #N ")" ::: "memory"); \
    SBAR

// prep: phase 1 builds W2[iq][m] fp32; phase 2 builds W2T bf16 [m][iq].
__global__ void clifford_prep(const float* __restrict__ weight,
                              float* __restrict__ W2,
                              unsigned short* __restrict__ W2T) {
    int t = threadIdx.x;
    for (int e = t; e < 4096; e += 256) {
        int o = e >> 9, i = (e >> 6) & 7, k = (e >> 3) & 7, p = e & 7;
        int q = (int)QTAB[k * 8 + p];
        float s = (float)SGN[k * 8 + p];
        W2[((i * 8 + q) * 64) + (o * 8 + k)] = s * weight[(o * 8 + i) * 8 + p];
    }
    __syncthreads();
    for (int e = t; e < 4096; e += 256) {
        int n = e >> 6, k = e & 63;
        __hip_bfloat16 h = __float2bfloat16(W2[k * 64 + n]);
        W2T[n * 64 + k] = *reinterpret_cast<unsigned short*>(&h);
    }
}

static __device__ __forceinline__ short f2bf(float f) {
    __hip_bfloat16 h = __float2bfloat16(f);
    return *reinterpret_cast<short*>(&h);
}

// x-chunk loaded as MFMA B-fragments (batch = column). Lane l supplies
// batch (bt*16 + (l&15)), k = kh*32 + 8*(l>>4) + e. Per instruction pair
// each batch-row contributes 128 B contiguous -> fully dense segments.
// (Addressing identical to R15's verified LOADA, mt -> bt.)
#define LOADB(CI, R)                                                         \
    {                                                                        \
        const float* b_ = x + (size_t)(CI) * 2048;                           \
        _Pragma("unroll") for (int bt_ = 0; bt_ < 2; ++bt_)                  \
        _Pragma("unroll") for (int kh_ = 0; kh_ < 2; ++kh_) {                \
            const float* p_ =                                                \
                b_ + (bt_ * 16 + (l & 15)) * 64 + kh_ * 32 + 8 * (l >> 4);   \
            R[bt_][kh_][0] = *(const f32x4*)p_;                              \
            R[bt_][kh_][1] = *(const f32x4*)(p_ + 4);                        \
        }                                                                    \
    }

// Swapped-operand MFMA: D = W2T(m x k) * x(k x b). acc[mt][bt], 4x2 tiles.
// A: w2t LDS (lane row m = mt*16+(l&15), k-run 8*(l>>4)) - same swizzled
//    reads as before. B: x from registers (lane col b, same k-run).
// D: row = m = mt*16+4*(l>>4)+reg, col = b = bt*16+(l&15) [m89-verified] ->
// lane holds 4 CONSECUTIVE m per tile -> direct f32x4 store, NO transpose.
#define COMPUTE(R)                                                           \
    {                                                                        \
        _Pragma("unroll") for (int kh = 0; kh < 2; ++kh) {                   \
            bf16x8 afr[4];                                                   \
            _Pragma("unroll") for (int mt = 0; mt < 4; ++mt) {               \
                int m_ = mt * 16 + (l & 15);                                 \
                int qb = kh * 4 + (l >> 4);                                  \
                afr[mt] = *(const bf16x8*)((const char*)w2t + m_ * 128 +     \
                                           (((qb ^ (m_ & 7))) << 4));        \
            }                                                                \
            _Pragma("unroll") for (int bt = 0; bt < 2; ++bt) {               \
                bf16x8 xf;                                                   \
                xf[0] = f2bf(R[bt][kh][0].x); xf[1] = f2bf(R[bt][kh][0].y);  \
                xf[2] = f2bf(R[bt][kh][0].z); xf[3] = f2bf(R[bt][kh][0].w);  \
                xf[4] = f2bf(R[bt][kh][1].x); xf[5] = f2bf(R[bt][kh][1].y);  \
                xf[6] = f2bf(R[bt][kh][1].z); xf[7] = f2bf(R[bt][kh][1].w);  \
                _Pragma("unroll") for (int mt = 0; mt < 4; ++mt) {           \
                    acc[mt][bt] = __builtin_amdgcn_mfma_f32_16x16x32_bf16(   \
                        afr[mt], xf, acc[mt][bt], 0, 0, 0);                  \
                }                                                            \
            }                                                                \
        }                                                                    \
    }

// Direct nt stores from the D-fragment: one f32x4 per tile; per
// instruction 16 batches x 64 B dense segments (R14-verified: WRITE stays
// exactly 512 MiB at 64-B granularity).
#define STORE_CHUNK(CI)                                                      \
    {                                                                        \
        float* ob_ = out + (size_t)(CI) * 2048;                              \
        _Pragma("unroll") for (int mt = 0; mt < 4; ++mt)                     \
        _Pragma("unroll") for (int bt = 0; bt < 2; ++bt) {                   \
            __builtin_nontemporal_store(                                     \
                acc[mt][bt],                                                 \
                (f32x4*)(ob_ + (bt * 16 + (l & 15)) * 64 + mt * 16 +         \
                         4 * (l >> 4)));                                     \
        }                                                                    \
    }

// acc rows are m -> bias folds in as a vector copy (4 consecutive m).
#define ACC_INIT                                                 \
    f32x4 acc[4][2];                                             \
    _Pragma("unroll") for (int mt = 0; mt < 4; ++mt)             \
    _Pragma("unroll") for (int bt = 0; bt < 2; ++bt)             \
        acc[mt][bt] = bvv4[mt];

__global__ __launch_bounds__(256) void clifford_main(
    const float* __restrict__ x, const unsigned short* __restrict__ W2T,
    const float* __restrict__ bias, float* __restrict__ out, int nB) {
    __shared__ __align__(16) unsigned short w2t[4096];  // 8 KB only

    const int tid = threadIdx.x;
    const int l = tid & 63;

    // ---- block-shared W2T init (swizzled 16-B quads), one barrier ----
#pragma unroll
    for (int gg = 0; gg < 2; ++gg) {
        int g = tid * 2 + gg;  // 512 quads
        int n = g >> 3, q = g & 7;
        u32x4 v = *(const u32x4*)(W2T + n * 64 + q * 8);
        *(u32x4*)((char*)w2t + n * 128 + ((q ^ (n & 7)) << 4)) = v;
    }
    __syncthreads();

    const int nC = nB >> 5;  // 32-row chunks
    const long long nW = (long long)gridDim.x * 4;
    const long long w = (long long)blockIdx.x * 4 + (tid >> 6);
    const int cpw = (int)(nC / nW);
    const long long rem = nC - (long long)cpw * nW;

    f32x4 bvv4[4];
#pragma unroll
    for (int mt = 0; mt < 4; ++mt)
        bvv4[mt] = *(const f32x4*)(bias + mt * 16 + 4 * (l >> 4));
#pragma unroll
    for (int mt = 0; mt < 4; ++mt) asm volatile("" : "+v"(bvv4[mt]));
    // pins drain the bias loads now -> vm queue below holds ONLY our ops

    f32x4 RA[2][2][2], RB[2][2][2];  // named double buffers (rule #20)
    const long long c0 = w * cpw;
    if (cpw >= 3) {
        LOADB(c0, RA);
        LOADB(c0 + 1, RB);
        WAITVM(8);  // RA resident; RB's 8 loads still in flight
        for (int i = 0; i < cpw - 2; ++i) {
            const long long c = c0 + i;
            ACC_INIT;
            if ((i & 1) == 0) {
                COMPUTE(RA);
                LOADB(c + 2, RA);  // prefetch before stores (WAR safe:
                                   // in-order issue; MFMA reads done)
                STORE_CHUNK(c);
            } else {
                COMPUTE(RB);
                LOADB(c + 2, RB);
                STORE_CHUNK(c);
            }
            // queue: [S(c-1):<=8, L(c+1):8, L(c+2):8, S(c):8]
            // -> vmcnt(16) retires S(c-1)+L(c+1); next buffer resident
            WAITVM(16);
        }
        {   // chunk c0+cpw-2 (its loads retired by last WAITVM(16))
            ACC_INIT;
            if (((cpw - 2) & 1) == 0) { COMPUTE(RA); } else { COMPUTE(RB); }
            STORE_CHUNK(c0 + cpw - 2);
            // queue: [S(cpw-3):8, L(cpw-1):8, S(cpw-2):8] -> vmcnt(8)
            // retires through L(cpw-1)
            WAITVM(8);
        }
        {   // final chunk
            ACC_INIT;
            if (((cpw - 1) & 1) == 0) { COMPUTE(RA); } else { COMPUTE(RB); }
            STORE_CHUNK(c0 + cpw - 1);
        }
    } else {
        for (int i = 0; i < cpw; ++i) {
            LOADB(c0 + i, RA);
            WAITVM(0);
            ACC_INIT;
            COMPUTE(RA);
            STORE_CHUNK(c0 + i);
            WAITVM(0);
        }
    }
    if (w < rem) {  // leftover chunks (0 at the bench shape)
        const long long c = nW * cpw + w;
        WAITVM(0);
        LOADB(c, RA);
        WAITVM(0);
        ACC_INIT;
        COMPUTE(RA);
        STORE_CHUNK(c);
    }
}

extern "C" void kernel_launch(void* const* d_in, const int* in_sizes, int n_in,
                              void* d_out, int out_size, void* d_ws,
                              size_t ws_size, hipStream_t stream) {
    const float* x = (const float*)d_in[0];
    const float* weight = (const float*)d_in[1];
    const float* bias = (const float*)d_in[2];
    float* out = (float*)d_out;
    float* W2 = (float*)d_ws;                              // 16 KB
    unsigned short* W2T = (unsigned short*)(W2 + 4096);    // +8 KB

    int nB = in_sizes[0] / 64;  // 4096*512 batch elements

    hipLaunchKernelGGL(clifford_prep, dim3(1), dim3(256), 0, stream, weight,
                       W2, W2T);
    int nC = nB >> 5;
    int blocks = 2048;  // 8192 waves -> 8 chunks/wave at nB=2^21
    if (blocks * 4 > nC) blocks = (nC + 3) / 4;
    if (blocks < 1) blocks = 1;
    hipLaunchKernelGGL(clifford_main, dim3(blocks), dim3(256), 0, stream, x,
                       W2T, bias, out, nB);
}

// Round 20
// 214.144 us; speedup vs baseline: 1.1717x; 1.1717x over previous
//
#include <hip/hip_runtime.h>
#include <hip/hip_bf16.h>
#include <stdint.h>

// T-structure as a signed permutation: for each (k,p) exactly one q with
// sign s such that T[k,p,q] = s. Transcribed from _TERMS.
__constant__ signed char QTAB[64] = {
    0,1,2,3,4,5,6,7,
    1,0,4,5,2,3,7,6,
    2,4,0,6,1,7,3,5,
    3,5,6,0,7,1,2,4,
    4,2,1,7,0,6,5,3,
    5,3,7,1,6,0,4,2,
    6,7,3,2,5,4,0,1,
    7,6,5,4,3,2,1,0};
__constant__ signed char SGN[64] = {
    1, 1, 1, 1,-1,-1,-1,-1,
    1, 1,-1, 1, 1,-1,-1,-1,
    1, 1, 1,-1,-1, 1, 1,-1,
    1,-1, 1, 1,-1,-1,-1, 1,
    1, 1,-1, 1, 1,-1, 1,-1,
    1,-1, 1, 1, 1, 1,-1,-1,
    1,-1,-1, 1,-1, 1, 1, 1,
    1, 1,-1, 1, 1,-1, 1, 1};

typedef __attribute__((ext_vector_type(8))) short bf16x8;
typedef __attribute__((ext_vector_type(4))) float f32x4;
typedef __attribute__((ext_vector_type(4))) unsigned int u32x4;

#define SBAR __builtin_amdgcn_sched_barrier(0)
#define WAITVM(N)                                         \
    asm volatile("s_waitcnt vmcnt(" #N ")" ::: "memory"); \
    SBAR

// prep: phase 1 builds W2[iq][m] fp32; phase 2 builds W2T bf16 [m][iq]
// for MFMA B-fragments (k-contiguous per output column).
__global__ void clifford_prep(const float* __restrict__ weight,
                              float* __restrict__ W2,
                              unsigned short* __restrict__ W2T) {
    int t = threadIdx.x;
    for (int e = t; e < 4096; e += 256) {
        int o = e >> 9, i = (e >> 6) & 7, k = (e >> 3) & 7, p = e & 7;
        int q = (int)QTAB[k * 8 + p];
        float s = (float)SGN[k * 8 + p];
        W2[((i * 8 + q) * 64) + (o * 8 + k)] = s * weight[(o * 8 + i) * 8 + p];
    }
    __syncthreads();
    for (int e = t; e < 4096; e += 256) {
        int n = e >> 6, k = e & 63;
        __hip_bfloat16 h = __float2bfloat16(W2[k * 64 + n]);
        W2T[n * 64 + k] = *reinterpret_cast<unsigned short*>(&h);
    }
}

static __device__ __forceinline__ short f2bf(float f) {
    __hip_bfloat16 h = __float2bfloat16(f);
    return *reinterpret_cast<short*>(&h);
}

// Direct global->VGPR A-fragment loads for one 32-row chunk (8 dwordx4).
// Lane l supplies row (mt*16 + (l&15)), k = kh*32 + 8*(l>>4) + e.
// Per instruction pair: each row contributes 128 B contiguous -> fully
// dense segments. No LDS, no swizzle. (R15-verified, absmax 0.125.)
#define LOADA(CI, R)                                                         \
    {                                                                        \
        const float* b_ = x + (size_t)(CI) * 2048;                           \
        _Pragma("unroll") for (int mt_ = 0; mt_ < 2; ++mt_)                  \
        _Pragma("unroll") for (int kh_ = 0; kh_ < 2; ++kh_) {                \
            const float* p_ =                                                \
                b_ + (mt_ * 16 + (l & 15)) * 64 + kh_ * 32 + 8 * (l >> 4);   \
            R[mt_][kh_][0] = *(const f32x4*)p_;                              \
            R[mt_][kh_][1] = *(const f32x4*)(p_ + 4);                        \
        }                                                                    \
    }

// MFMA compute from register A-fragments: acc[mt][nt], 2x4 tiles of 16x16.
// B: block-shared swizzled W2T LDS; lane holds col nt*16+(l&15).
// D: col = l&15, row = 4*(l>>4)+reg  [m89-verified, R13-verified].
#define COMPUTE(R)                                                           \
    {                                                                        \
        _Pragma("unroll") for (int kh = 0; kh < 2; ++kh) {                   \
            bf16x8 afr[2];                                                   \
            _Pragma("unroll") for (int mt = 0; mt < 2; ++mt) {               \
                bf16x8 a_;                                                   \
                a_[0] = f2bf(R[mt][kh][0].x); a_[1] = f2bf(R[mt][kh][0].y);  \
                a_[2] = f2bf(R[mt][kh][0].z); a_[3] = f2bf(R[mt][kh][0].w);  \
                a_[4] = f2bf(R[mt][kh][1].x); a_[5] = f2bf(R[mt][kh][1].y);  \
                a_[6] = f2bf(R[mt][kh][1].z); a_[7] = f2bf(R[mt][kh][1].w);  \
                afr[mt] = a_;                                                \
            }                                                                \
            _Pragma("unroll") for (int nt = 0; nt < 4; ++nt) {               \
                int n_ = nt * 16 + (l & 15);                                 \
                int qb = kh * 4 + (l >> 4);                                  \
                bf16x8 bfr = *(const bf16x8*)((const char*)w2t + n_ * 128 +  \
                                              (((qb ^ (n_ & 7))) << 4));     \
                acc[0][nt] = __builtin_amdgcn_mfma_f32_16x16x32_bf16(        \
                    afr[0], bfr, acc[0][nt], 0, 0, 0);                       \
                acc[1][nt] = __builtin_amdgcn_mfma_f32_16x16x32_bf16(        \
                    afr[1], bfr, acc[1][nt], 0, 0, 0);                       \
            }                                                                \
        }                                                                    \
    }

// Transpose acc through the per-wave LDS staging buffer, then 1-KB
// coalesced non-temporal dwordx4 stores (out is write-once, never re-read:
// stream past L2 to cut evict interference with the x read stream).
// f32x4 (clang ext-vector) is required by __builtin_nontemporal_store.
#define STORE_CHUNK(CI)                                                      \
    {                                                                        \
        _Pragma("unroll") for (int mt = 0; mt < 2; ++mt)                     \
        _Pragma("unroll") for (int nt = 0; nt < 4; ++nt)                     \
        _Pragma("unroll") for (int rg = 0; rg < 4; ++rg) {                   \
            int row_ = mt * 16 + 4 * (l >> 4) + rg;                          \
            sg[row_ * 64 + nt * 16 + (l & 15)] = acc[mt][nt][rg];            \
        }                                                                    \
        float* ob_ = out + (size_t)(CI) * 2048;                              \
        _Pragma("unroll") for (int j_ = 0; j_ < 8; ++j_) {                   \
            f32x4 v_ = *(const f32x4*)(sg + j_ * 256 + 4 * l);               \
            __builtin_nontemporal_store(v_,                                  \
                                        (f32x4*)(ob_ + j_ * 256 + 4 * l));   \
        }                                                                    \
    }

#define ACC_INIT                                                 \
    f32x4 acc[2][4];                                             \
    _Pragma("unroll") for (int mt = 0; mt < 2; ++mt)             \
    _Pragma("unroll") for (int nt = 0; nt < 4; ++nt) {           \
        acc[mt][nt][0] = bvv[nt]; acc[mt][nt][1] = bvv[nt];      \
        acc[mt][nt][2] = bvv[nt]; acc[mt][nt][3] = bvv[nt];      \
    }

__global__ __launch_bounds__(256) void clifford_main(
    const float* __restrict__ x, const unsigned short* __restrict__ W2T,
    const float* __restrict__ bias, float* __restrict__ out, int nB) {
    __shared__ __align__(16) float stg[4][2048];          // 32 KB staging
    __shared__ __align__(16) unsigned short w2t[4096];    // 8 KB, swizzled

    const int tid = threadIdx.x;
    const int l = tid & 63;
    const int wv = tid >> 6;

    // ---- block-shared W2T init (swizzled 16-B quads), one barrier ----
#pragma unroll
    for (int gg = 0; gg < 2; ++gg) {
        int g = tid * 2 + gg;  // 512 quads
        int n = g >> 3, q = g & 7;
        u32x4 v = *(const u32x4*)(W2T + n * 64 + q * 8);
        *(u32x4*)((char*)w2t + n * 128 + ((q ^ (n & 7)) << 4)) = v;
    }
    __syncthreads();

    float* sg = stg[wv];
    const int nC = nB >> 5;  // 32-row chunks
    const long long nW = (long long)gridDim.x * 4;
    const long long w = (long long)blockIdx.x * 4 + wv;
    const int cpw = (int)(nC / nW);
    const long long rem = nC - (long long)cpw * nW;

    float bvv[4];
#pragma unroll
    for (int nt = 0; nt < 4; ++nt) bvv[nt] = bias[nt * 16 + (l & 15)];
#pragma unroll
    for (int nt = 0; nt < 4; ++nt) asm volatile("" : "+v"(bvv[nt]));
    // pins drain the bias loads now -> vm queue below holds ONLY our ops

    f32x4 RA[2][2][2], RB[2][2][2];  // named double buffers (rule #20)
    const long long c0 = w * cpw;
    if (cpw >= 3) {
        LOADA(c0, RA);
        LOADA(c0 + 1, RB);
        WAITVM(8);  // RA resident; RB's 8 loads still in flight
        for (int i = 0; i < cpw - 2; ++i) {
            const long long c = c0 + i;
            ACC_INIT;
            if ((i & 1) == 0) {
                COMPUTE(RA);
                LOADA(c + 2, RA);  // issue BEFORE the store block: next-next
                                   // read burst in flight during the LDS
                                   // transpose (WAR safe: in-order issue)
                STORE_CHUNK(c);
            } else {
                COMPUTE(RB);
                LOADA(c + 2, RB);
                STORE_CHUNK(c);
            }
            // queue: [S(c-1):<=8, L(c+1):8, L(c+2):8, S(c):8]
            // -> vmcnt(16) retires S(c-1)+L(c+1); next buffer resident
            WAITVM(16);
        }
        {   // chunk c0+cpw-2 (its loads retired by last WAITVM(16))
            ACC_INIT;
            if (((cpw - 2) & 1) == 0) { COMPUTE(RA); } else { COMPUTE(RB); }
            STORE_CHUNK(c0 + cpw - 2);
            // queue: [S(cpw-3):8, L(cpw-1):8, S(cpw-2):8] -> vmcnt(8)
            // retires through L(cpw-1)
            WAITVM(8);
        }
        {   // final chunk
            ACC_INIT;
            if (((cpw - 1) & 1) == 0) { COMPUTE(RA); } else { COMPUTE(RB); }
            STORE_CHUNK(c0 + cpw - 1);
        }
    } else {
        for (int i = 0; i < cpw; ++i) {
            LOADA(c0 + i, RA);
            WAITVM(0);
            ACC_INIT;
            COMPUTE(RA);
            STORE_CHUNK(c0 + i);
            WAITVM(0);
        }
    }
    if (w < rem) {  // leftover chunks (0 at the bench shape)
        const long long c = nW * cpw + w;
        WAITVM(0);
        LOADA(c, RA);
        WAITVM(0);
        ACC_INIT;
        COMPUTE(RA);
        STORE_CHUNK(c);
    }
}

extern "C" void kernel_launch(void* const* d_in, const int* in_sizes, int n_in,
                              void* d_out, int out_size, void* d_ws,
                              size_t ws_size, hipStream_t stream) {
    const float* x = (const float*)d_in[0];
    const float* weight = (const float*)d_in[1];
    const float* bias = (const float*)d_in[2];
    float* out = (float*)d_out;
    float* W2 = (float*)d_ws;                              // 16 KB
    unsigned short* W2T = (unsigned short*)(W2 + 4096);    // +8 KB

    int nB = in_sizes[0] / 64;  // 4096*512 batch elements

    hipLaunchKernelGGL(clifford_prep, dim3(1), dim3(256), 0, stream, weight,
                       W2, W2T);
    int nC = nB >> 5;
    int blocks = 2048;  // 8192 waves -> 8 chunks/wave at nB=2^21
    if (blocks * 4 > nC) blocks = (nC + 3) / 4;
    if (blocks < 1) blocks = 1;
    hipLaunchKernelGGL(clifford_main, dim3(blocks), dim3(256), 0, stream, x,
                       W2T, bias, out, nB);
}